// Round 6
// baseline (1189.757 us; speedup 1.0000x reference)
//
#include <hip/hip_runtime.h>

// DGM forward, MI355X. bf16 MFMA 16x16x32, fp32 accum, fp32 tanh.
// R6: R5 + triple-fused Z/R/G gemm (Z,R share Sb A-frags; G reads S1b) for 3x
//     in-wave memory-level parallelism at the proven (256,2)/VGPR=128 regime.
//     H's first-kb B-frags manually prefetched before B1 so the barrier window
//     and epilogue tanh work cover their L2 latency.
//     M=32/WG, 256 thr, wave w owns cols [w*64,w*64+64). LDS 33KB.
//
// MFMA 16x16x32 layouts (ln = lane, q = ln>>4, c15 = ln&15):
//  A-frag: lane holds A[m=c15][k=kb*32+q*8+i], i=0..7
//  B-frag: lane holds B[k=kb*32+q*8+i][n=cblk*16+c15]
//  C/D:    lane holds C[row=q*4+ii][col=c15]
// W packed (d_ws) B-frag order per matrix: idx = (((cblk*8+kb)*64+ln)*8+i)
// LDS state swizzle: elem(r,k) -> r*256 + (((k>>3)^r)&31)*8 + (k&7)

typedef __attribute__((ext_vector_type(8))) short bf16x8;
typedef __attribute__((ext_vector_type(4))) float f32x4;

__device__ __forceinline__ short f2bf(float f) {
    unsigned u = __float_as_uint(f);
    unsigned r = (u + 0x7FFFu + ((u >> 16) & 1u)) >> 16;
    return (short)r;
}
__device__ __forceinline__ float bf2f(short h) {
    return __uint_as_float(((unsigned)(unsigned short)h) << 16);
}
__device__ __forceinline__ float fast_tanh(float x) {
    float e = __expf(2.0f * x);
    return 1.0f - 2.0f * __builtin_amdgcn_rcpf(e + 1.0f);
}
__device__ __forceinline__ int sw_off(int r, int k) {
    return r * 256 + ((((k >> 3) ^ r) & 31) << 3) + (k & 7);
}
__device__ __forceinline__ unsigned pk2(float a, float b) {
    return (unsigned)(unsigned short)f2bf(a) | ((unsigned)(unsigned short)f2bf(b) << 16);
}
__device__ __forceinline__ float upk(unsigned p, int hi) {
    return __uint_as_float(hi ? (p & 0xFFFF0000u) : (p << 16));
}

// ---------------- pack weights fp32 -> bf16, B-frag order ----------------
__global__ void pack_w(const float* __restrict__ Wz, const float* __restrict__ Wg,
                       const float* __restrict__ Wr, const float* __restrict__ Wh,
                       short* __restrict__ out) {
    int idx = blockIdx.x * 256 + threadIdx.x;   // 12*65536 threads
    int mat = idx >> 16;                        // 0..11 = l*4+g
    int e   = idx & 65535;
    int l = mat >> 2, g = mat & 3;
    int i  = e & 7;
    int ln = (e >> 3) & 63;
    int kb = (e >> 9) & 7;
    int c  = e >> 12;
    int k = kb * 32 + (ln >> 4) * 8 + i;
    int n = c * 16 + (ln & 15);
    const float* W = (g == 0) ? Wz : (g == 1) ? Wg : (g == 2) ? Wr : Wh;
    out[idx] = f2bf(W[l * 65536 + k * 256 + n]);
}

// ---------------- main kernel: 32 rows/WG, 256 threads ----------------
__global__ __launch_bounds__(256, 2)
void dgm_main(const float* __restrict__ T, const float* __restrict__ X,
              const float* __restrict__ W0, const float* __restrict__ b0,
              const float* __restrict__ Uz, const float* __restrict__ Ug,
              const float* __restrict__ Ur, const float* __restrict__ Uh,
              const float* __restrict__ bz, const float* __restrict__ bg,
              const float* __restrict__ br, const float* __restrict__ bh,
              const float* __restrict__ Wf, const float* __restrict__ bfp,
              const short* __restrict__ Wp, float* __restrict__ out) {
    __shared__ __align__(16) short Sb[8192];    // 16 KB: S (holds S*R mid-layer)
    __shared__ __align__(16) short S1b[8192];   // 16 KB: S1, immutable
    __shared__ float2 txS[32];

    const int tid = threadIdx.x;
    const int w   = tid >> 6;        // 0..3
    const int ln  = tid & 63;
    const int q   = ln >> 4;
    const int c15 = ln & 15;
    const int m0  = blockIdx.x * 32;

    if (tid < 32) txS[tid] = make_float2(T[m0 + tid], X[m0 + tid]);
    __syncthreads();

    // ---- S1 = tanh(X@W0 + b0); S = S1.  One column per thread, 32 rows. ----
    {
        float w00 = W0[tid], w01 = W0[256 + tid], bb = b0[tid];
#pragma unroll 4
        for (int r = 0; r < 32; r++) {
            float2 tx = txS[r];
            short v = f2bf(fast_tanh(tx.x * w00 + tx.y * w01 + bb));
            int off = sw_off(r, tid);
            S1b[off] = v;
            Sb[off]  = v;
        }
    }
    __syncthreads();

    // per-thread row t/x values (C-layout rows rb*16 + q*4 + ii)
    float2 tx[8];
#pragma unroll
    for (int rb = 0; rb < 2; rb++)
#pragma unroll
        for (int ii = 0; ii < 4; ii++) tx[rb * 4 + ii] = txS[rb * 16 + q * 4 + ii];

    // register mirror of this thread's owned S elements (C-layout), packed bf16
    unsigned sreg[2][4][2];
#pragma unroll
    for (int rb = 0; rb < 2; rb++)
#pragma unroll
        for (int cb = 0; cb < 4; cb++) {
            int col = (w * 4 + cb) * 16 + c15;
#pragma unroll
            for (int p = 0; p < 2; p++) {
                unsigned lo = (unsigned short)Sb[sw_off(rb * 16 + q * 4 + 2 * p,     col)];
                unsigned hi = (unsigned short)Sb[sw_off(rb * 16 + q * 4 + 2 * p + 1, col)];
                sreg[rb][cb][p] = lo | (hi << 16);
            }
        }

    // ---- layers ----
    for (int l = 0; l < 3; l++) {
        const short* Wzp = Wp + (l * 4 + 0) * 65536;
        const short* Wgp = Wp + (l * 4 + 1) * 65536;
        const short* Wrp = Wp + (l * 4 + 2) * 65536;
        const short* Whp = Wp + (l * 4 + 3) * 65536;

        unsigned zsp[2][4][2], srp[2][4][2], gmp[2][4][2];

        // ===== fused Z + R + G GEMMs (Z,R: A from Sb; G: A from S1b) =====
        {
            f32x4 zacc[2][4], racc[2][4], gacc[2][4];
#pragma unroll
            for (int cb = 0; cb < 4; cb++) {
                int col = (w * 4 + cb) * 16 + c15;
                float uz0 = Uz[l * 512 + col], uz1 = Uz[l * 512 + 256 + col];
                float ur0 = Ur[l * 512 + col], ur1 = Ur[l * 512 + 256 + col];
                float ug0 = Ug[l * 512 + col], ug1 = Ug[l * 512 + 256 + col];
                float bbz = bz[l * 256 + col], bbr = br[l * 256 + col], bbg = bg[l * 256 + col];
#pragma unroll
                for (int rb = 0; rb < 2; rb++)
#pragma unroll
                    for (int ii = 0; ii < 4; ii++) {
                        float tt = tx[rb * 4 + ii].x, xx = tx[rb * 4 + ii].y;
                        zacc[rb][cb][ii] = bbz + tt * uz0 + xx * uz1;
                        racc[rb][cb][ii] = bbr + tt * ur0 + xx * ur1;
                        gacc[rb][cb][ii] = bbg + tt * ug0 + xx * ug1;
                    }
            }
#pragma unroll
            for (int kb = 0; kb < 8; kb++) {
                bf16x8 as[2], ag[2];
#pragma unroll
                for (int rb = 0; rb < 2; rb++) {
                    int r = rb * 16 + c15;
                    int ao = r * 256 + ((((kb * 4 + q) ^ r) & 31) << 3);
                    as[rb] = *(const bf16x8*)(Sb  + ao);
                    ag[rb] = *(const bf16x8*)(S1b + ao);
                }
#pragma unroll
                for (int cb = 0; cb < 4; cb++) {
                    int bo = (((w * 4 + cb) * 8 + kb) * 64 + ln) << 3;
                    bf16x8 bzf = *(const bf16x8*)(Wzp + bo);
                    bf16x8 brf = *(const bf16x8*)(Wrp + bo);
                    bf16x8 bgf = *(const bf16x8*)(Wgp + bo);
#pragma unroll
                    for (int rb = 0; rb < 2; rb++) {
                        zacc[rb][cb] = __builtin_amdgcn_mfma_f32_16x16x32_bf16(as[rb], bzf, zacc[rb][cb], 0, 0, 0);
                        racc[rb][cb] = __builtin_amdgcn_mfma_f32_16x16x32_bf16(as[rb], brf, racc[rb][cb], 0, 0, 0);
                        gacc[rb][cb] = __builtin_amdgcn_mfma_f32_16x16x32_bf16(ag[rb], bgf, gacc[rb][cb], 0, 0, 0);
                    }
                }
            }

            // epilogues: zs = tanh(Z)*S_old ; sr = S_old*tanh(R) ; gm = 1-tanh(G)
#pragma unroll
            for (int rb = 0; rb < 2; rb++)
#pragma unroll
                for (int cb = 0; cb < 4; cb++)
#pragma unroll
                    for (int p = 0; p < 2; p++) {
                        float s0 = upk(sreg[rb][cb][p], 0), s1 = upk(sreg[rb][cb][p], 1);
                        zsp[rb][cb][p] = pk2(fast_tanh(zacc[rb][cb][2 * p])     * s0,
                                             fast_tanh(zacc[rb][cb][2 * p + 1]) * s1);
                        srp[rb][cb][p] = pk2(fast_tanh(racc[rb][cb][2 * p])     * s0,
                                             fast_tanh(racc[rb][cb][2 * p + 1]) * s1);
                        gmp[rb][cb][p] = pk2(1.0f - fast_tanh(gacc[rb][cb][2 * p]),
                                             1.0f - fast_tanh(gacc[rb][cb][2 * p + 1]));
                    }
        }

        // prefetch H's first-kb B-frags (global loads, legal before the barrier)
        bf16x8 hb[4];
#pragma unroll
        for (int cb = 0; cb < 4; cb++)
            hb[cb] = *(const bf16x8*)(Whp + ((((w * 4 + cb) * 8 + 0) * 64 + ln) << 3));

        __syncthreads();   // B1: all Sb reads (Z,R A-frags) done
#pragma unroll
        for (int rb = 0; rb < 2; rb++)
#pragma unroll
            for (int cb = 0; cb < 4; cb++) {
                int col = (w * 4 + cb) * 16 + c15;
#pragma unroll
                for (int p = 0; p < 2; p++) {
                    Sb[sw_off(rb * 16 + q * 4 + 2 * p,     col)] = (short)(srp[rb][cb][p] & 0xFFFFu);
                    Sb[sw_off(rb * 16 + q * 4 + 2 * p + 1, col)] = (short)(srp[rb][cb][p] >> 16);
                }
            }
        __syncthreads();   // B2: Sb = S*R visible

        // ===== H GEMM (A from Sb = S*R; kb=0 B-frags prefetched) =====
        {
            f32x4 hacc[2][4];
#pragma unroll
            for (int cb = 0; cb < 4; cb++) {
                int col = (w * 4 + cb) * 16 + c15;
                float u0 = Uh[l * 512 + col], u1 = Uh[l * 512 + 256 + col];
                float bb = bh[l * 256 + col];
#pragma unroll
                for (int rb = 0; rb < 2; rb++)
#pragma unroll
                    for (int ii = 0; ii < 4; ii++)
                        hacc[rb][cb][ii] = bb + tx[rb * 4 + ii].x * u0 + tx[rb * 4 + ii].y * u1;
            }
#pragma unroll
            for (int kb = 0; kb < 8; kb++) {
                bf16x8 a[2];
#pragma unroll
                for (int rb = 0; rb < 2; rb++) {
                    int r = rb * 16 + c15;
                    a[rb] = *(const bf16x8*)(Sb + r * 256 + ((((kb * 4 + q) ^ r) & 31) << 3));
                }
#pragma unroll
                for (int cb = 0; cb < 4; cb++) {
                    bf16x8 b = (kb == 0) ? hb[cb]
                        : *(const bf16x8*)(Whp + ((((w * 4 + cb) * 8 + kb) * 64 + ln) << 3));
#pragma unroll
                    for (int rb = 0; rb < 2; rb++)
                        hacc[rb][cb] = __builtin_amdgcn_mfma_f32_16x16x32_bf16(a[rb], b, hacc[rb][cb], 0, 0, 0);
                }
            }

            // S_new = (1-G)*tanh(H) + zs
#pragma unroll
            for (int rb = 0; rb < 2; rb++)
#pragma unroll
                for (int cb = 0; cb < 4; cb++)
#pragma unroll
                    for (int p = 0; p < 2; p++) {
                        float sn0 = upk(gmp[rb][cb][p], 0) * fast_tanh(hacc[rb][cb][2 * p])
                                  + upk(zsp[rb][cb][p], 0);
                        float sn1 = upk(gmp[rb][cb][p], 1) * fast_tanh(hacc[rb][cb][2 * p + 1])
                                  + upk(zsp[rb][cb][p], 1);
                        srp[rb][cb][p] = pk2(sn0, sn1);
                    }
        }

        __syncthreads();   // B3: all H A-frag reads of Sb done
#pragma unroll
        for (int rb = 0; rb < 2; rb++)
#pragma unroll
            for (int cb = 0; cb < 4; cb++) {
                int col = (w * 4 + cb) * 16 + c15;
#pragma unroll
                for (int p = 0; p < 2; p++) {
                    Sb[sw_off(rb * 16 + q * 4 + 2 * p,     col)] = (short)(srp[rb][cb][p] & 0xFFFFu);
                    Sb[sw_off(rb * 16 + q * 4 + 2 * p + 1, col)] = (short)(srp[rb][cb][p] >> 16);
                    sreg[rb][cb][p] = srp[rb][cb][p];
                }
            }
        __syncthreads();   // B4: new S visible
    }

    // ---- out = S @ Wf + bf : 8 threads/row, vectorized LDS reads ----
    {
        int row = tid >> 3;
        int seg = tid & 7;
        float sum = 0.0f;
#pragma unroll
        for (int j = 0; j < 4; j++) {
            int ch = seg * 4 + j;
            bf16x8 sv = *(const bf16x8*)(Sb + row * 256 + (((ch ^ row) & 31) << 3));
            float4 wa = *(const float4*)(Wf + ch * 8);
            float4 wb = *(const float4*)(Wf + ch * 8 + 4);
            sum += bf2f(sv[0]) * wa.x + bf2f(sv[1]) * wa.y + bf2f(sv[2]) * wa.z + bf2f(sv[3]) * wa.w
                 + bf2f(sv[4]) * wb.x + bf2f(sv[5]) * wb.y + bf2f(sv[6]) * wb.z + bf2f(sv[7]) * wb.w;
        }
        sum += __shfl_down(sum, 4, 8);
        sum += __shfl_down(sum, 2, 8);
        sum += __shfl_down(sum, 1, 8);
        if (seg == 0) out[m0 + row] = sum + bfp[0];
    }
}

extern "C" void kernel_launch(void* const* d_in, const int* in_sizes, int n_in,
                              void* d_out, int out_size, void* d_ws, size_t ws_size,
                              hipStream_t stream) {
    const float* T  = (const float*)d_in[0];
    const float* X  = (const float*)d_in[1];
    const float* W0 = (const float*)d_in[2];
    const float* b0 = (const float*)d_in[3];
    const float* Uz = (const float*)d_in[4];
    const float* Ug = (const float*)d_in[5];
    const float* Ur = (const float*)d_in[6];
    const float* Uh = (const float*)d_in[7];
    const float* Wz = (const float*)d_in[8];
    const float* Wg = (const float*)d_in[9];
    const float* Wr = (const float*)d_in[10];
    const float* Wh = (const float*)d_in[11];
    const float* bz = (const float*)d_in[12];
    const float* bg = (const float*)d_in[13];
    const float* br = (const float*)d_in[14];
    const float* bh = (const float*)d_in[15];
    const float* Wf = (const float*)d_in[16];
    const float* bfp= (const float*)d_in[17];
    float* out = (float*)d_out;
    short* Wp = (short*)d_ws;           // 12*65536 bf16 = 1.5 MB
    const int N = in_sizes[0];

    pack_w<<<(12 * 65536) / 256, 256, 0, stream>>>(Wz, Wg, Wr, Wh, Wp);
    dgm_main<<<N / 32, 256, 0, stream>>>(T, X, W0, b0, Uz, Ug, Ur, Uh,
                                         bz, bg, br, bh, Wf, bfp, Wp, out);
}

// Round 7
// 798.030 us; speedup vs baseline: 1.4909x; 1.4909x over previous
//
#include <hip/hip_runtime.h>

// DGM forward, MI355X. bf16 MFMA 16x16x32, fp32 accum, fp32 tanh.
// R7: M=64 rows/WG via 512 threads (8 waves); wave w owns cols [w*32,w*32+32)
//     (2 col-blocks) x 64 rows (4 row-blocks). Per-wave register footprint is
//     IDENTICAL to the proven no-spill R5: 32 f32 acc (one gate at a time),
//     64 packed bf16 state regs, sequential Z,R,G(S1b) epilogues before B1.
//     Each B-frag now feeds 4 MFMAs (vs 2) -> B-frag L2 traffic per row halves.
//     __launch_bounds__(512,1) == 8 waves/CU min == the (256,2) no-spill regime.
//     LDS = Sb(32K)+S1b(32K)+txS = 64.5KB; one WG/CU (VGPR-limited anyway).
//
// MFMA 16x16x32 layouts (ln = lane, q = ln>>4, c15 = ln&15):
//  A-frag: lane holds A[m=c15][k=kb*32+q*8+i], i=0..7
//  B-frag: lane holds B[k=kb*32+q*8+i][n=cblk*16+c15]
//  C/D:    lane holds C[row=q*4+ii][col=c15]
// W packed (d_ws) B-frag order per matrix: idx = (((cblk*8+kb)*64+ln)*8+i)
// LDS state swizzle: elem(r,k) -> r*256 + (((k>>3)^r)&31)*8 + (k&7)

typedef __attribute__((ext_vector_type(8))) short bf16x8;
typedef __attribute__((ext_vector_type(4))) float f32x4;

__device__ __forceinline__ short f2bf(float f) {
    unsigned u = __float_as_uint(f);
    unsigned r = (u + 0x7FFFu + ((u >> 16) & 1u)) >> 16;
    return (short)r;
}
__device__ __forceinline__ float bf2f(short h) {
    return __uint_as_float(((unsigned)(unsigned short)h) << 16);
}
__device__ __forceinline__ float fast_tanh(float x) {
    float e = __expf(2.0f * x);
    return 1.0f - 2.0f * __builtin_amdgcn_rcpf(e + 1.0f);
}
__device__ __forceinline__ int sw_off(int r, int k) {
    return r * 256 + ((((k >> 3) ^ r) & 31) << 3) + (k & 7);
}
__device__ __forceinline__ unsigned pk2(float a, float b) {
    return (unsigned)(unsigned short)f2bf(a) | ((unsigned)(unsigned short)f2bf(b) << 16);
}
__device__ __forceinline__ float upk(unsigned p, int hi) {
    return __uint_as_float(hi ? (p & 0xFFFF0000u) : (p << 16));
}

// ---------------- pack weights fp32 -> bf16, B-frag order ----------------
__global__ void pack_w(const float* __restrict__ Wz, const float* __restrict__ Wg,
                       const float* __restrict__ Wr, const float* __restrict__ Wh,
                       short* __restrict__ out) {
    int idx = blockIdx.x * 256 + threadIdx.x;   // 12*65536 threads
    int mat = idx >> 16;                        // 0..11 = l*4+g
    int e   = idx & 65535;
    int l = mat >> 2, g = mat & 3;
    int i  = e & 7;
    int ln = (e >> 3) & 63;
    int kb = (e >> 9) & 7;
    int c  = e >> 12;
    int k = kb * 32 + (ln >> 4) * 8 + i;
    int n = c * 16 + (ln & 15);
    const float* W = (g == 0) ? Wz : (g == 1) ? Wg : (g == 2) ? Wr : Wh;
    out[idx] = f2bf(W[l * 65536 + k * 256 + n]);
}

// ---------------- one gate GEMM: acc = bias + X@U + In@W ----------------
// wave w covers cols [w*32, w*32+32) (cb=0..1), rows 0..63 (rb=0..3)
__device__ __forceinline__ void gate_gemm(const short* __restrict__ In,   // LDS [64][256] swizzled
                                          const short* __restrict__ Wm,   // packed bf16 65536
                                          const float* __restrict__ U,    // [2][256] fp32
                                          const float* __restrict__ bias, // [256]
                                          const float2* __restrict__ txS, // LDS [64]
                                          int q, int c15, int w,
                                          f32x4 acc[4][2]) {
    // init: bias + t*U0 + x*U1
    float u0[2], u1[2], bb[2];
#pragma unroll
    for (int cb = 0; cb < 2; cb++) {
        int col = (w * 2 + cb) * 16 + c15;
        u0[cb] = U[col]; u1[cb] = U[256 + col]; bb[cb] = bias[col];
    }
#pragma unroll
    for (int rb = 0; rb < 4; rb++)
#pragma unroll
        for (int ii = 0; ii < 4; ii++) {
            float2 tx = txS[rb * 16 + q * 4 + ii];
#pragma unroll
            for (int cb = 0; cb < 2; cb++)
                acc[rb][cb][ii] = bb[cb] + tx.x * u0[cb] + tx.y * u1[cb];
        }
#pragma unroll
    for (int kb = 0; kb < 8; kb++) {
        bf16x8 a[4];
#pragma unroll
        for (int rb = 0; rb < 4; rb++) {
            int r = rb * 16 + c15;
            a[rb] = *(const bf16x8*)(In + r * 256 + ((((kb * 4 + q) ^ r) & 31) << 3));
        }
#pragma unroll
        for (int cb = 0; cb < 2; cb++) {
            bf16x8 b = *(const bf16x8*)(Wm + ((((w * 2 + cb) * 8 + kb) * 64 + (q * 16 + c15)) << 3));
#pragma unroll
            for (int rb = 0; rb < 4; rb++)
                acc[rb][cb] = __builtin_amdgcn_mfma_f32_16x16x32_bf16(a[rb], b, acc[rb][cb], 0, 0, 0);
        }
    }
}

// ---------------- main kernel: 64 rows/WG, 512 threads ----------------
__global__ __launch_bounds__(512, 1)
void dgm_main(const float* __restrict__ T, const float* __restrict__ X,
              const float* __restrict__ W0, const float* __restrict__ b0,
              const float* __restrict__ Uz, const float* __restrict__ Ug,
              const float* __restrict__ Ur, const float* __restrict__ Uh,
              const float* __restrict__ bz, const float* __restrict__ bg,
              const float* __restrict__ br, const float* __restrict__ bh,
              const float* __restrict__ Wf, const float* __restrict__ bfp,
              const short* __restrict__ Wp, float* __restrict__ out) {
    __shared__ __align__(16) short Sb[16384];    // 32 KB: S (holds S*R mid-layer)
    __shared__ __align__(16) short S1b[16384];   // 32 KB: S1, immutable
    __shared__ float2 txS[64];

    const int tid = threadIdx.x;
    const int w   = tid >> 6;        // 0..7
    const int ln  = tid & 63;
    const int q   = ln >> 4;
    const int c15 = ln & 15;
    const int m0  = blockIdx.x * 64;

    if (tid < 64) txS[tid] = make_float2(T[m0 + tid], X[m0 + tid]);
    __syncthreads();

    // ---- S1 = tanh(X@W0 + b0); S = S1. col = tid&255, 32 rows per thread. ----
    {
        int col = tid & 255;
        int r0  = (tid >> 8) << 5;
        float w00 = W0[col], w01 = W0[256 + col], bb = b0[col];
#pragma unroll 4
        for (int rr = 0; rr < 32; rr++) {
            int r = r0 + rr;
            float2 tx = txS[r];
            short v = f2bf(fast_tanh(tx.x * w00 + tx.y * w01 + bb));
            int off = sw_off(r, col);
            S1b[off] = v;
            Sb[off]  = v;
        }
    }
    __syncthreads();

    // register mirror of this thread's owned S elements (C-layout), packed bf16
    unsigned sreg[4][2][2];
#pragma unroll
    for (int rb = 0; rb < 4; rb++)
#pragma unroll
        for (int cb = 0; cb < 2; cb++) {
            int col = (w * 2 + cb) * 16 + c15;
#pragma unroll
            for (int p = 0; p < 2; p++) {
                unsigned lo = (unsigned short)Sb[sw_off(rb * 16 + q * 4 + 2 * p,     col)];
                unsigned hi = (unsigned short)Sb[sw_off(rb * 16 + q * 4 + 2 * p + 1, col)];
                sreg[rb][cb][p] = lo | (hi << 16);
            }
        }

    // ---- layers ----
    for (int l = 0; l < 3; l++) {
        const short* Wzp = Wp + (l * 4 + 0) * 65536;
        const short* Wgp = Wp + (l * 4 + 1) * 65536;
        const short* Wrp = Wp + (l * 4 + 2) * 65536;
        const short* Whp = Wp + (l * 4 + 3) * 65536;

        f32x4 acc[4][2];
        unsigned zsp[4][2][2], srp[4][2][2], gmp[4][2][2];

        // Z gate: zs = tanh(Z)*S_old
        gate_gemm(Sb, Wzp, Uz + l * 512, bz + l * 256, txS, q, c15, w, acc);
#pragma unroll
        for (int rb = 0; rb < 4; rb++)
#pragma unroll
            for (int cb = 0; cb < 2; cb++)
#pragma unroll
                for (int p = 0; p < 2; p++)
                    zsp[rb][cb][p] = pk2(
                        fast_tanh(acc[rb][cb][2 * p])     * upk(sreg[rb][cb][p], 0),
                        fast_tanh(acc[rb][cb][2 * p + 1]) * upk(sreg[rb][cb][p], 1));

        // R gate: sr = S_old*tanh(R)
        gate_gemm(Sb, Wrp, Ur + l * 512, br + l * 256, txS, q, c15, w, acc);
#pragma unroll
        for (int rb = 0; rb < 4; rb++)
#pragma unroll
            for (int cb = 0; cb < 2; cb++)
#pragma unroll
                for (int p = 0; p < 2; p++)
                    srp[rb][cb][p] = pk2(
                        fast_tanh(acc[rb][cb][2 * p])     * upk(sreg[rb][cb][p], 0),
                        fast_tanh(acc[rb][cb][2 * p + 1]) * upk(sreg[rb][cb][p], 1));

        // G gate (reads only S1b)
        gate_gemm(S1b, Wgp, Ug + l * 512, bg + l * 256, txS, q, c15, w, acc);
#pragma unroll
        for (int rb = 0; rb < 4; rb++)
#pragma unroll
            for (int cb = 0; cb < 2; cb++)
#pragma unroll
                for (int p = 0; p < 2; p++)
                    gmp[rb][cb][p] = pk2(1.0f - fast_tanh(acc[rb][cb][2 * p]),
                                         1.0f - fast_tanh(acc[rb][cb][2 * p + 1]));

        // prefetch H's first-kb B-frag (global load, legal before the barrier)
        bf16x8 hb[2];
#pragma unroll
        for (int cb = 0; cb < 2; cb++)
            hb[cb] = *(const bf16x8*)(Whp + ((((w * 2 + cb) * 8 + 0) * 64 + (q * 16 + c15)) << 3));

        __syncthreads();   // B1: all Sb reads (Z,R A-frags) done
#pragma unroll
        for (int rb = 0; rb < 4; rb++)
#pragma unroll
            for (int cb = 0; cb < 2; cb++) {
                int col = (w * 2 + cb) * 16 + c15;
#pragma unroll
                for (int p = 0; p < 2; p++) {
                    Sb[sw_off(rb * 16 + q * 4 + 2 * p,     col)] = (short)(srp[rb][cb][p] & 0xFFFFu);
                    Sb[sw_off(rb * 16 + q * 4 + 2 * p + 1, col)] = (short)(srp[rb][cb][p] >> 16);
                }
            }
        __syncthreads();   // B2: Sb = S*R visible

        // H gate (reads Sb = S*R; kb=0 B-frags prefetched)
        {
            float u0[2], u1[2], bb[2];
#pragma unroll
            for (int cb = 0; cb < 2; cb++) {
                int col = (w * 2 + cb) * 16 + c15;
                u0[cb] = Uh[l * 512 + col]; u1[cb] = Uh[l * 512 + 256 + col]; bb[cb] = bh[l * 256 + col];
            }
#pragma unroll
            for (int rb = 0; rb < 4; rb++)
#pragma unroll
                for (int ii = 0; ii < 4; ii++) {
                    float2 tx = txS[rb * 16 + q * 4 + ii];
#pragma unroll
                    for (int cb = 0; cb < 2; cb++)
                        acc[rb][cb][ii] = bb[cb] + tx.x * u0[cb] + tx.y * u1[cb];
                }
#pragma unroll
            for (int kb = 0; kb < 8; kb++) {
                bf16x8 a[4];
#pragma unroll
                for (int rb = 0; rb < 4; rb++) {
                    int r = rb * 16 + c15;
                    a[rb] = *(const bf16x8*)(Sb + r * 256 + ((((kb * 4 + q) ^ r) & 31) << 3));
                }
#pragma unroll
                for (int cb = 0; cb < 2; cb++) {
                    bf16x8 b = (kb == 0) ? hb[cb]
                        : *(const bf16x8*)(Whp + ((((w * 2 + cb) * 8 + kb) * 64 + (q * 16 + c15)) << 3));
#pragma unroll
                    for (int rb = 0; rb < 4; rb++)
                        acc[rb][cb] = __builtin_amdgcn_mfma_f32_16x16x32_bf16(a[rb], b, acc[rb][cb], 0, 0, 0);
                }
            }
        }

        // S_new = (1-G)*tanh(H) + zs  (no Sb access here)
#pragma unroll
        for (int rb = 0; rb < 4; rb++)
#pragma unroll
            for (int cb = 0; cb < 2; cb++)
#pragma unroll
                for (int p = 0; p < 2; p++) {
                    float sn0 = upk(gmp[rb][cb][p], 0) * fast_tanh(acc[rb][cb][2 * p])
                              + upk(zsp[rb][cb][p], 0);
                    float sn1 = upk(gmp[rb][cb][p], 1) * fast_tanh(acc[rb][cb][2 * p + 1])
                              + upk(zsp[rb][cb][p], 1);
                    srp[rb][cb][p] = pk2(sn0, sn1);
                }

        __syncthreads();   // B3: all H A-frag reads of Sb done
#pragma unroll
        for (int rb = 0; rb < 4; rb++)
#pragma unroll
            for (int cb = 0; cb < 2; cb++) {
                int col = (w * 2 + cb) * 16 + c15;
#pragma unroll
                for (int p = 0; p < 2; p++) {
                    Sb[sw_off(rb * 16 + q * 4 + 2 * p,     col)] = (short)(srp[rb][cb][p] & 0xFFFFu);
                    Sb[sw_off(rb * 16 + q * 4 + 2 * p + 1, col)] = (short)(srp[rb][cb][p] >> 16);
                    sreg[rb][cb][p] = srp[rb][cb][p];
                }
            }
        __syncthreads();   // B4: new S visible
    }

    // ---- out = S @ Wf + bf : 8 threads/row, vectorized LDS reads ----
    {
        int row = tid >> 3;
        int seg = tid & 7;
        float sum = 0.0f;
#pragma unroll
        for (int j = 0; j < 4; j++) {
            int ch = seg * 4 + j;
            bf16x8 sv = *(const bf16x8*)(Sb + row * 256 + (((ch ^ row) & 31) << 3));
            float4 wa = *(const float4*)(Wf + ch * 8);
            float4 wb = *(const float4*)(Wf + ch * 8 + 4);
            sum += bf2f(sv[0]) * wa.x + bf2f(sv[1]) * wa.y + bf2f(sv[2]) * wa.z + bf2f(sv[3]) * wa.w
                 + bf2f(sv[4]) * wb.x + bf2f(sv[5]) * wb.y + bf2f(sv[6]) * wb.z + bf2f(sv[7]) * wb.w;
        }
        sum += __shfl_down(sum, 4, 8);
        sum += __shfl_down(sum, 2, 8);
        sum += __shfl_down(sum, 1, 8);
        if (seg == 0) out[m0 + row] = sum + bfp[0];
    }
}

extern "C" void kernel_launch(void* const* d_in, const int* in_sizes, int n_in,
                              void* d_out, int out_size, void* d_ws, size_t ws_size,
                              hipStream_t stream) {
    const float* T  = (const float*)d_in[0];
    const float* X  = (const float*)d_in[1];
    const float* W0 = (const float*)d_in[2];
    const float* b0 = (const float*)d_in[3];
    const float* Uz = (const float*)d_in[4];
    const float* Ug = (const float*)d_in[5];
    const float* Ur = (const float*)d_in[6];
    const float* Uh = (const float*)d_in[7];
    const float* Wz = (const float*)d_in[8];
    const float* Wg = (const float*)d_in[9];
    const float* Wr = (const float*)d_in[10];
    const float* Wh = (const float*)d_in[11];
    const float* bz = (const float*)d_in[12];
    const float* bg = (const float*)d_in[13];
    const float* br = (const float*)d_in[14];
    const float* bh = (const float*)d_in[15];
    const float* Wf = (const float*)d_in[16];
    const float* bfp= (const float*)d_in[17];
    float* out = (float*)d_out;
    short* Wp = (short*)d_ws;           // 12*65536 bf16 = 1.5 MB
    const int N = in_sizes[0];

    pack_w<<<(12 * 65536) / 256, 256, 0, stream>>>(Wz, Wg, Wr, Wh, Wp);
    dgm_main<<<N / 64, 512, 0, stream>>>(T, X, W0, b0, Uz, Ug, Ur, Uh,
                                         bz, bg, br, bh, Wf, bfp, Wp, out);
}

// Round 9
// 689.213 us; speedup vs baseline: 1.7263x; 1.1579x over previous
//
#include <hip/hip_runtime.h>

// DGM forward, MI355X. bf16 MFMA 16x16x32, fp32 accum, fp32 tanh.
// R9: 1024-thread WG (16 waves), M=64 rows/WG; wave w owns ONE col-block
//     (cols [w*16, w*16+16)) x 4 row-blocks (rows 0..63).
//     Per-thread live state: acc 16 f32 (one gate at a time), packed bf16
//     state 32 regs (zs/sr/gm/sreg), A-frags 16, B-frag 4 -> ~100 live,
//     safely under the 128-VGPR no-spill cap.
//     __launch_bounds__(1024,1): 1 block/CU * 16 waves = 4 waves/SIMD
//     -> 512/4 = 128 VGPR budget (same no-spill regime as proven (256,2)).
//     Occupancy doubles vs R5 (8 -> 16 waves/CU); M=64 halves per-row weight
//     traffic (each B-frag feeds 4 MFMAs).
//     SRb eliminated via zs = Z*S_old trick; LDS = Sb(32K)+S1b(32K)+txS.
//
// MFMA 16x16x32 layouts (ln = lane, q = ln>>4, c15 = ln&15):
//  A-frag: lane holds A[m=c15][k=kb*32+q*8+i], i=0..7
//  B-frag: lane holds B[k=kb*32+q*8+i][n=cblk*16+c15]
//  C/D:    lane holds C[row=q*4+ii][col=c15]
// W packed (d_ws) B-frag order per matrix: idx = (((cblk*8+kb)*64+ln)*8+i)
// LDS state swizzle: elem(r,k) -> r*256 + (((k>>3)^r)&31)*8 + (k&7)

typedef __attribute__((ext_vector_type(8))) short bf16x8;
typedef __attribute__((ext_vector_type(4))) float f32x4;

__device__ __forceinline__ short f2bf(float f) {
    unsigned u = __float_as_uint(f);
    unsigned r = (u + 0x7FFFu + ((u >> 16) & 1u)) >> 16;
    return (short)r;
}
__device__ __forceinline__ float bf2f(short h) {
    return __uint_as_float(((unsigned)(unsigned short)h) << 16);
}
__device__ __forceinline__ float fast_tanh(float x) {
    float e = __expf(2.0f * x);
    return 1.0f - 2.0f * __builtin_amdgcn_rcpf(e + 1.0f);
}
__device__ __forceinline__ int sw_off(int r, int k) {
    return r * 256 + ((((k >> 3) ^ r) & 31) << 3) + (k & 7);
}
__device__ __forceinline__ unsigned pk2(float a, float b) {
    return (unsigned)(unsigned short)f2bf(a) | ((unsigned)(unsigned short)f2bf(b) << 16);
}
__device__ __forceinline__ float upk(unsigned p, int hi) {
    return __uint_as_float(hi ? (p & 0xFFFF0000u) : (p << 16));
}

// ---------------- pack weights fp32 -> bf16, B-frag order ----------------
__global__ void pack_w(const float* __restrict__ Wz, const float* __restrict__ Wg,
                       const float* __restrict__ Wr, const float* __restrict__ Wh,
                       short* __restrict__ out) {
    int idx = blockIdx.x * 256 + threadIdx.x;   // 12*65536 threads
    int mat = idx >> 16;                        // 0..11 = l*4+g
    int e   = idx & 65535;
    int l = mat >> 2, g = mat & 3;
    int i  = e & 7;
    int ln = (e >> 3) & 63;
    int kb = (e >> 9) & 7;
    int c  = e >> 12;
    int k = kb * 32 + (ln >> 4) * 8 + i;
    int n = c * 16 + (ln & 15);
    const float* W = (g == 0) ? Wz : (g == 1) ? Wg : (g == 2) ? Wr : Wh;
    out[idx] = f2bf(W[l * 65536 + k * 256 + n]);
}

// ---------------- one gate GEMM: acc = bias + X@U + In@W ----------------
// wave w covers cols [w*16, w*16+16) (one col-block), rows 0..63 (rb=0..3)
__device__ __forceinline__ void gate_gemm(const short* __restrict__ In,   // LDS [64][256] swizzled
                                          const short* __restrict__ Wm,   // packed bf16 65536
                                          const float* __restrict__ U,    // [2][256] fp32
                                          const float* __restrict__ bias, // [256]
                                          const float2* __restrict__ txS, // LDS [64]
                                          int q, int c15, int w, int ln,
                                          f32x4 acc[4]) {
    // init: bias + t*U0 + x*U1
    {
        int col = w * 16 + c15;
        float u0 = U[col], u1 = U[256 + col], bb = bias[col];
#pragma unroll
        for (int rb = 0; rb < 4; rb++)
#pragma unroll
            for (int ii = 0; ii < 4; ii++) {
                float2 tx = txS[rb * 16 + q * 4 + ii];
                acc[rb][ii] = bb + tx.x * u0 + tx.y * u1;
            }
    }
#pragma unroll
    for (int kb = 0; kb < 8; kb++) {
        bf16x8 a[4];
#pragma unroll
        for (int rb = 0; rb < 4; rb++) {
            int r = rb * 16 + c15;
            a[rb] = *(const bf16x8*)(In + r * 256 + ((((kb * 4 + q) ^ r) & 31) << 3));
        }
        bf16x8 b = *(const bf16x8*)(Wm + (((w * 8 + kb) * 64 + ln) << 3));
#pragma unroll
        for (int rb = 0; rb < 4; rb++)
            acc[rb] = __builtin_amdgcn_mfma_f32_16x16x32_bf16(a[rb], b, acc[rb], 0, 0, 0);
    }
}

// ---------------- main kernel: 64 rows/WG, 1024 threads ----------------
__global__ __launch_bounds__(1024, 1)
void dgm_main(const float* __restrict__ T, const float* __restrict__ X,
              const float* __restrict__ W0, const float* __restrict__ b0,
              const float* __restrict__ Uz, const float* __restrict__ Ug,
              const float* __restrict__ Ur, const float* __restrict__ Uh,
              const float* __restrict__ bz, const float* __restrict__ bg,
              const float* __restrict__ br, const float* __restrict__ bh,
              const float* __restrict__ Wf, const float* __restrict__ bfp,
              const short* __restrict__ Wp, float* __restrict__ out) {
    __shared__ __align__(16) short Sb[16384];    // 32 KB: S (holds S*R mid-layer)
    __shared__ __align__(16) short S1b[16384];   // 32 KB: S1, immutable
    __shared__ float2 txS[64];

    const int tid = threadIdx.x;
    const int w   = tid >> 6;        // 0..15 (= col-block)
    const int ln  = tid & 63;
    const int q   = ln >> 4;
    const int c15 = ln & 15;
    const int m0  = blockIdx.x * 64;

    if (tid < 64) txS[tid] = make_float2(T[m0 + tid], X[m0 + tid]);
    __syncthreads();

    // ---- S1 = tanh(X@W0 + b0); S = S1. col = tid&255; 16 rows per thread. ----
    {
        int col = tid & 255;
        int r0  = (tid >> 8) << 4;
        float w00 = W0[col], w01 = W0[256 + col], bb = b0[col];
#pragma unroll 4
        for (int rr = 0; rr < 16; rr++) {
            int r = r0 + rr;
            float2 tx = txS[r];
            short v = f2bf(fast_tanh(tx.x * w00 + tx.y * w01 + bb));
            int off = sw_off(r, col);
            S1b[off] = v;
            Sb[off]  = v;
        }
    }
    __syncthreads();

    // register mirror of this thread's owned S elements (C-layout), packed bf16
    // owned: rows rb*16 + q*4 + ii (rb=0..3), col = w*16 + c15
    const int col_ = w * 16 + c15;
    unsigned sreg[4][2];
#pragma unroll
    for (int rb = 0; rb < 4; rb++)
#pragma unroll
        for (int p = 0; p < 2; p++) {
            unsigned lo = (unsigned short)Sb[sw_off(rb * 16 + q * 4 + 2 * p,     col_)];
            unsigned hi = (unsigned short)Sb[sw_off(rb * 16 + q * 4 + 2 * p + 1, col_)];
            sreg[rb][p] = lo | (hi << 16);
        }

    // ---- layers ----
    for (int l = 0; l < 3; l++) {
        const short* Wzp = Wp + (l * 4 + 0) * 65536;
        const short* Wgp = Wp + (l * 4 + 1) * 65536;
        const short* Wrp = Wp + (l * 4 + 2) * 65536;
        const short* Whp = Wp + (l * 4 + 3) * 65536;

        f32x4 acc[4];
        unsigned zsp[4][2], srp[4][2], gmp[4][2];

        // Z gate: zs = tanh(Z)*S_old
        gate_gemm(Sb, Wzp, Uz + l * 512, bz + l * 256, txS, q, c15, w, ln, acc);
#pragma unroll
        for (int rb = 0; rb < 4; rb++)
#pragma unroll
            for (int p = 0; p < 2; p++)
                zsp[rb][p] = pk2(
                    fast_tanh(acc[rb][2 * p])     * upk(sreg[rb][p], 0),
                    fast_tanh(acc[rb][2 * p + 1]) * upk(sreg[rb][p], 1));

        // R gate: sr = S_old*tanh(R)
        gate_gemm(Sb, Wrp, Ur + l * 512, br + l * 256, txS, q, c15, w, ln, acc);
#pragma unroll
        for (int rb = 0; rb < 4; rb++)
#pragma unroll
            for (int p = 0; p < 2; p++)
                srp[rb][p] = pk2(
                    fast_tanh(acc[rb][2 * p])     * upk(sreg[rb][p], 0),
                    fast_tanh(acc[rb][2 * p + 1]) * upk(sreg[rb][p], 1));

        // G gate (reads only S1b)
        gate_gemm(S1b, Wgp, Ug + l * 512, bg + l * 256, txS, q, c15, w, ln, acc);
#pragma unroll
        for (int rb = 0; rb < 4; rb++)
#pragma unroll
            for (int p = 0; p < 2; p++)
                gmp[rb][p] = pk2(1.0f - fast_tanh(acc[rb][2 * p]),
                                 1.0f - fast_tanh(acc[rb][2 * p + 1]));

        __syncthreads();   // B1: all Sb reads (Z,R A-frags) done
#pragma unroll
        for (int rb = 0; rb < 4; rb++)
#pragma unroll
            for (int p = 0; p < 2; p++) {
                Sb[sw_off(rb * 16 + q * 4 + 2 * p,     col_)] = (short)(srp[rb][p] & 0xFFFFu);
                Sb[sw_off(rb * 16 + q * 4 + 2 * p + 1, col_)] = (short)(srp[rb][p] >> 16);
            }
        __syncthreads();   // B2: Sb = S*R visible

        // H gate (reads Sb = S*R)
        gate_gemm(Sb, Whp, Uh + l * 512, bh + l * 256, txS, q, c15, w, ln, acc);

        // S_new = (1-G)*tanh(H) + zs  (no Sb access here)
#pragma unroll
        for (int rb = 0; rb < 4; rb++)
#pragma unroll
            for (int p = 0; p < 2; p++) {
                float sn0 = upk(gmp[rb][p], 0) * fast_tanh(acc[rb][2 * p]) + upk(zsp[rb][p], 0);
                float sn1 = upk(gmp[rb][p], 1) * fast_tanh(acc[rb][2 * p + 1]) + upk(zsp[rb][p], 1);
                srp[rb][p] = pk2(sn0, sn1);
            }

        __syncthreads();   // B3: all H A-frag reads of Sb done
#pragma unroll
        for (int rb = 0; rb < 4; rb++)
#pragma unroll
            for (int p = 0; p < 2; p++) {
                Sb[sw_off(rb * 16 + q * 4 + 2 * p,     col_)] = (short)(srp[rb][p] & 0xFFFFu);
                Sb[sw_off(rb * 16 + q * 4 + 2 * p + 1, col_)] = (short)(srp[rb][p] >> 16);
                sreg[rb][p] = srp[rb][p];
            }
        __syncthreads();   // B4: new S visible
    }

    // ---- out = S @ Wf + bf : 16 threads/row (seg covers 16 cols = 2 chunks) ----
    {
        int row = tid >> 4;       // 0..63
        int seg = tid & 15;       // 0..15
        float sum = 0.0f;
#pragma unroll
        for (int j = 0; j < 2; j++) {
            int ch = seg * 2 + j;
            bf16x8 sv = *(const bf16x8*)(Sb + row * 256 + (((ch ^ row) & 31) << 3));
            float4 wa = *(const float4*)(Wf + ch * 8);
            float4 wb = *(const float4*)(Wf + ch * 8 + 4);
            sum += bf2f(sv[0]) * wa.x + bf2f(sv[1]) * wa.y + bf2f(sv[2]) * wa.z + bf2f(sv[3]) * wa.w
                 + bf2f(sv[4]) * wb.x + bf2f(sv[5]) * wb.y + bf2f(sv[6]) * wb.z + bf2f(sv[7]) * wb.w;
        }
        sum += __shfl_down(sum, 8, 16);
        sum += __shfl_down(sum, 4, 16);
        sum += __shfl_down(sum, 2, 16);
        sum += __shfl_down(sum, 1, 16);
        if (seg == 0) out[m0 + row] = sum + bfp[0];
    }
}

extern "C" void kernel_launch(void* const* d_in, const int* in_sizes, int n_in,
                              void* d_out, int out_size, void* d_ws, size_t ws_size,
                              hipStream_t stream) {
    const float* T  = (const float*)d_in[0];
    const float* X  = (const float*)d_in[1];
    const float* W0 = (const float*)d_in[2];
    const float* b0 = (const float*)d_in[3];
    const float* Uz = (const float*)d_in[4];
    const float* Ug = (const float*)d_in[5];
    const float* Ur = (const float*)d_in[6];
    const float* Uh = (const float*)d_in[7];
    const float* Wz = (const float*)d_in[8];
    const float* Wg = (const float*)d_in[9];
    const float* Wr = (const float*)d_in[10];
    const float* Wh = (const float*)d_in[11];
    const float* bz = (const float*)d_in[12];
    const float* bg = (const float*)d_in[13];
    const float* br = (const float*)d_in[14];
    const float* bh = (const float*)d_in[15];
    const float* Wf = (const float*)d_in[16];
    const float* bfp= (const float*)d_in[17];
    float* out = (float*)d_out;
    short* Wp = (short*)d_ws;           // 12*65536 bf16 = 1.5 MB
    const int N = in_sizes[0];

    pack_w<<<(12 * 65536) / 256, 256, 0, stream>>>(Wz, Wg, Wr, Wh, Wp);
    dgm_main<<<N / 64, 1024, 0, stream>>>(T, X, W0, b0, Uz, Ug, Ur, Uh,
                                          bz, bg, br, bh, Wf, bfp, Wp, out);
}

// Round 10
// 599.384 us; speedup vs baseline: 1.9850x; 1.1499x over previous
//
#include <hip/hip_runtime.h>

// DGM forward, MI355X. bf16 MFMA 16x16x32, fp32 accum, fp32 tanh.
// R10: R9 (1024 thr, 16 waves/CU, M=64, wave w owns ONE col-block) slimmed to
//      the 64-arch-VGPR budget that (1024,1) implies (total 128/wave incl AGPR):
//      - sreg dropped: S_old re-read from Sb (scalar LDS) in Z/R epilogues
//      - zsp moved to LDS ZsB[8][1024] (lane-contiguous, conflict-free)
//      - only srp+gmp (16 regs) persist across gemms; acc (16) in AGPR half
//      Arch live ~56 <= 64 -> no spill at 16 waves/CU (47% occupancy).
//      LDS = Sb(32K)+S1b(32K)+ZsB(32K)+txS = ~97KB, 1 WG/CU.
//
// MFMA 16x16x32 layouts (ln = lane, q = ln>>4, c15 = ln&15):
//  A-frag: lane holds A[m=c15][k=kb*32+q*8+i], i=0..7
//  B-frag: lane holds B[k=kb*32+q*8+i][n=cblk*16+c15]
//  C/D:    lane holds C[row=q*4+ii][col=c15]
// W packed (d_ws) B-frag order per matrix: idx = (((cblk*8+kb)*64+ln)*8+i)
// LDS state swizzle: elem(r,k) -> r*256 + (((k>>3)^r)&31)*8 + (k&7)

typedef __attribute__((ext_vector_type(8))) short bf16x8;
typedef __attribute__((ext_vector_type(4))) float f32x4;

__device__ __forceinline__ short f2bf(float f) {
    unsigned u = __float_as_uint(f);
    unsigned r = (u + 0x7FFFu + ((u >> 16) & 1u)) >> 16;
    return (short)r;
}
__device__ __forceinline__ float bf2f(short h) {
    return __uint_as_float(((unsigned)(unsigned short)h) << 16);
}
__device__ __forceinline__ float fast_tanh(float x) {
    float e = __expf(2.0f * x);
    return 1.0f - 2.0f * __builtin_amdgcn_rcpf(e + 1.0f);
}
__device__ __forceinline__ int sw_off(int r, int k) {
    return r * 256 + ((((k >> 3) ^ r) & 31) << 3) + (k & 7);
}
__device__ __forceinline__ unsigned pk2(float a, float b) {
    return (unsigned)(unsigned short)f2bf(a) | ((unsigned)(unsigned short)f2bf(b) << 16);
}
__device__ __forceinline__ float upk(unsigned p, int hi) {
    return __uint_as_float(hi ? (p & 0xFFFF0000u) : (p << 16));
}

// ---------------- pack weights fp32 -> bf16, B-frag order ----------------
__global__ void pack_w(const float* __restrict__ Wz, const float* __restrict__ Wg,
                       const float* __restrict__ Wr, const float* __restrict__ Wh,
                       short* __restrict__ out) {
    int idx = blockIdx.x * 256 + threadIdx.x;   // 12*65536 threads
    int mat = idx >> 16;                        // 0..11 = l*4+g
    int e   = idx & 65535;
    int l = mat >> 2, g = mat & 3;
    int i  = e & 7;
    int ln = (e >> 3) & 63;
    int kb = (e >> 9) & 7;
    int c  = e >> 12;
    int k = kb * 32 + (ln >> 4) * 8 + i;
    int n = c * 16 + (ln & 15);
    const float* W = (g == 0) ? Wz : (g == 1) ? Wg : (g == 2) ? Wr : Wh;
    out[idx] = f2bf(W[l * 65536 + k * 256 + n]);
}

// ---------------- one gate GEMM: acc = bias + X@U + In@W ----------------
// wave w covers cols [w*16, w*16+16) (one col-block), rows 0..63 (rb=0..3)
__device__ __forceinline__ void gate_gemm(const short* __restrict__ In,   // LDS [64][256] swizzled
                                          const short* __restrict__ Wm,   // packed bf16 65536
                                          const float* __restrict__ U,    // [2][256] fp32
                                          const float* __restrict__ bias, // [256]
                                          const float2* __restrict__ txS, // LDS [64]
                                          int q, int c15, int w, int ln,
                                          f32x4 acc[4]) {
    // init: bias + t*U0 + x*U1
    {
        int col = w * 16 + c15;
        float u0 = U[col], u1 = U[256 + col], bb = bias[col];
#pragma unroll
        for (int rb = 0; rb < 4; rb++)
#pragma unroll
            for (int ii = 0; ii < 4; ii++) {
                float2 tx = txS[rb * 16 + q * 4 + ii];
                acc[rb][ii] = bb + tx.x * u0 + tx.y * u1;
            }
    }
#pragma unroll
    for (int kb = 0; kb < 8; kb++) {
        bf16x8 a[4];
#pragma unroll
        for (int rb = 0; rb < 4; rb++) {
            int r = rb * 16 + c15;
            a[rb] = *(const bf16x8*)(In + r * 256 + ((((kb * 4 + q) ^ r) & 31) << 3));
        }
        bf16x8 b = *(const bf16x8*)(Wm + (((w * 8 + kb) * 64 + ln) << 3));
#pragma unroll
        for (int rb = 0; rb < 4; rb++)
            acc[rb] = __builtin_amdgcn_mfma_f32_16x16x32_bf16(a[rb], b, acc[rb], 0, 0, 0);
    }
}

// ---------------- main kernel: 64 rows/WG, 1024 threads ----------------
__global__ __launch_bounds__(1024, 1)
void dgm_main(const float* __restrict__ T, const float* __restrict__ X,
              const float* __restrict__ W0, const float* __restrict__ b0,
              const float* __restrict__ Uz, const float* __restrict__ Ug,
              const float* __restrict__ Ur, const float* __restrict__ Uh,
              const float* __restrict__ bz, const float* __restrict__ bg,
              const float* __restrict__ br, const float* __restrict__ bh,
              const float* __restrict__ Wf, const float* __restrict__ bfp,
              const short* __restrict__ Wp, float* __restrict__ out) {
    __shared__ __align__(16) short Sb[16384];      // 32 KB: S (holds S*R mid-layer)
    __shared__ __align__(16) short S1b[16384];     // 32 KB: S1, immutable
    __shared__ unsigned ZsB[8][1024];              // 32 KB: zs = Z*S_old, per-thread slots
    __shared__ float2 txS[64];

    const int tid = threadIdx.x;
    const int w   = tid >> 6;        // 0..15 (= col-block)
    const int ln  = tid & 63;
    const int q   = ln >> 4;
    const int c15 = ln & 15;
    const int m0  = blockIdx.x * 64;

    if (tid < 64) txS[tid] = make_float2(T[m0 + tid], X[m0 + tid]);
    __syncthreads();

    // ---- S1 = tanh(X@W0 + b0); S = S1. col = tid&255; 16 rows per thread. ----
    {
        int col = tid & 255;
        int r0  = (tid >> 8) << 4;
        float w00 = W0[col], w01 = W0[256 + col], bb = b0[col];
#pragma unroll 4
        for (int rr = 0; rr < 16; rr++) {
            int r = r0 + rr;
            float2 tx = txS[r];
            short v = f2bf(fast_tanh(tx.x * w00 + tx.y * w01 + bb));
            int off = sw_off(r, col);
            S1b[off] = v;
            Sb[off]  = v;
        }
    }
    __syncthreads();

    const int col_ = w * 16 + c15;   // this thread's owned column

    // ---- layers ----
    for (int l = 0; l < 3; l++) {
        const short* Wzp = Wp + (l * 4 + 0) * 65536;
        const short* Wgp = Wp + (l * 4 + 1) * 65536;
        const short* Wrp = Wp + (l * 4 + 2) * 65536;
        const short* Whp = Wp + (l * 4 + 3) * 65536;

        f32x4 acc[4];
        unsigned srp[4][2], gmp[4][2];

        // Z gate: zs = tanh(Z)*S_old -> LDS ZsB (transient S_old read from Sb)
        gate_gemm(Sb, Wzp, Uz + l * 512, bz + l * 256, txS, q, c15, w, ln, acc);
#pragma unroll
        for (int rb = 0; rb < 4; rb++)
#pragma unroll
            for (int p = 0; p < 2; p++) {
                float s0 = bf2f(Sb[sw_off(rb * 16 + q * 4 + 2 * p,     col_)]);
                float s1 = bf2f(Sb[sw_off(rb * 16 + q * 4 + 2 * p + 1, col_)]);
                ZsB[rb * 2 + p][tid] = pk2(fast_tanh(acc[rb][2 * p])     * s0,
                                           fast_tanh(acc[rb][2 * p + 1]) * s1);
            }

        // R gate: sr = S_old*tanh(R)  (S_old re-read, transient)
        gate_gemm(Sb, Wrp, Ur + l * 512, br + l * 256, txS, q, c15, w, ln, acc);
#pragma unroll
        for (int rb = 0; rb < 4; rb++)
#pragma unroll
            for (int p = 0; p < 2; p++) {
                float s0 = bf2f(Sb[sw_off(rb * 16 + q * 4 + 2 * p,     col_)]);
                float s1 = bf2f(Sb[sw_off(rb * 16 + q * 4 + 2 * p + 1, col_)]);
                srp[rb][p] = pk2(fast_tanh(acc[rb][2 * p])     * s0,
                                 fast_tanh(acc[rb][2 * p + 1]) * s1);
            }

        // G gate (reads only S1b)
        gate_gemm(S1b, Wgp, Ug + l * 512, bg + l * 256, txS, q, c15, w, ln, acc);
#pragma unroll
        for (int rb = 0; rb < 4; rb++)
#pragma unroll
            for (int p = 0; p < 2; p++)
                gmp[rb][p] = pk2(1.0f - fast_tanh(acc[rb][2 * p]),
                                 1.0f - fast_tanh(acc[rb][2 * p + 1]));

        __syncthreads();   // B1: all Sb reads (Z,R A-frags + epilogue S_old) done
#pragma unroll
        for (int rb = 0; rb < 4; rb++)
#pragma unroll
            for (int p = 0; p < 2; p++) {
                Sb[sw_off(rb * 16 + q * 4 + 2 * p,     col_)] = (short)(srp[rb][p] & 0xFFFFu);
                Sb[sw_off(rb * 16 + q * 4 + 2 * p + 1, col_)] = (short)(srp[rb][p] >> 16);
            }
        __syncthreads();   // B2: Sb = S*R visible

        // H gate (reads Sb = S*R)
        gate_gemm(Sb, Whp, Uh + l * 512, bh + l * 256, txS, q, c15, w, ln, acc);

        // S_new = (1-G)*tanh(H) + zs  (zs from LDS; no Sb access here)
#pragma unroll
        for (int rb = 0; rb < 4; rb++)
#pragma unroll
            for (int p = 0; p < 2; p++) {
                unsigned zs = ZsB[rb * 2 + p][tid];
                float sn0 = upk(gmp[rb][p], 0) * fast_tanh(acc[rb][2 * p])     + upk(zs, 0);
                float sn1 = upk(gmp[rb][p], 1) * fast_tanh(acc[rb][2 * p + 1]) + upk(zs, 1);
                srp[rb][p] = pk2(sn0, sn1);
            }

        __syncthreads();   // B3: all H A-frag reads of Sb done
#pragma unroll
        for (int rb = 0; rb < 4; rb++)
#pragma unroll
            for (int p = 0; p < 2; p++) {
                Sb[sw_off(rb * 16 + q * 4 + 2 * p,     col_)] = (short)(srp[rb][p] & 0xFFFFu);
                Sb[sw_off(rb * 16 + q * 4 + 2 * p + 1, col_)] = (short)(srp[rb][p] >> 16);
            }
        __syncthreads();   // B4: new S visible
    }

    // ---- out = S @ Wf + bf : 16 threads/row (seg covers 16 cols = 2 chunks) ----
    {
        int row = tid >> 4;       // 0..63
        int seg = tid & 15;       // 0..15
        float sum = 0.0f;
#pragma unroll
        for (int j = 0; j < 2; j++) {
            int ch = seg * 2 + j;
            bf16x8 sv = *(const bf16x8*)(Sb + row * 256 + (((ch ^ row) & 31) << 3));
            float4 wa = *(const float4*)(Wf + ch * 8);
            float4 wb = *(const float4*)(Wf + ch * 8 + 4);
            sum += bf2f(sv[0]) * wa.x + bf2f(sv[1]) * wa.y + bf2f(sv[2]) * wa.z + bf2f(sv[3]) * wa.w
                 + bf2f(sv[4]) * wb.x + bf2f(sv[5]) * wb.y + bf2f(sv[6]) * wb.z + bf2f(sv[7]) * wb.w;
        }
        sum += __shfl_down(sum, 8, 16);
        sum += __shfl_down(sum, 4, 16);
        sum += __shfl_down(sum, 2, 16);
        sum += __shfl_down(sum, 1, 16);
        if (seg == 0) out[m0 + row] = sum + bfp[0];
    }
}

extern "C" void kernel_launch(void* const* d_in, const int* in_sizes, int n_in,
                              void* d_out, int out_size, void* d_ws, size_t ws_size,
                              hipStream_t stream) {
    const float* T  = (const float*)d_in[0];
    const float* X  = (const float*)d_in[1];
    const float* W0 = (const float*)d_in[2];
    const float* b0 = (const float*)d_in[3];
    const float* Uz = (const float*)d_in[4];
    const float* Ug = (const float*)d_in[5];
    const float* Ur = (const float*)d_in[6];
    const float* Uh = (const float*)d_in[7];
    const float* Wz = (const float*)d_in[8];
    const float* Wg = (const float*)d_in[9];
    const float* Wr = (const float*)d_in[10];
    const float* Wh = (const float*)d_in[11];
    const float* bz = (const float*)d_in[12];
    const float* bg = (const float*)d_in[13];
    const float* br = (const float*)d_in[14];
    const float* bh = (const float*)d_in[15];
    const float* Wf = (const float*)d_in[16];
    const float* bfp= (const float*)d_in[17];
    float* out = (float*)d_out;
    short* Wp = (short*)d_ws;           // 12*65536 bf16 = 1.5 MB
    const int N = in_sizes[0];

    pack_w<<<(12 * 65536) / 256, 256, 0, stream>>>(Wz, Wg, Wr, Wh, Wp);
    dgm_main<<<N / 64, 1024, 0, stream>>>(T, X, W0, b0, Uz, Ug, Ur, Uh,
                                          bz, bg, br, bh, Wf, bfp, Wp, out);
}